// Round 15
// baseline (455.827 us; speedup 1.0000x reference)
//
#include <hip/hip_runtime.h>
#include <hip/hip_bf16.h>
#include <math.h>

#define N_NODES 100000
#define N_EDGES 1600000
#define N_FEAT 32
#define HIDDEN 128
#define N_GRAPHS 256
#define LN_EPS 1e-5f

// CSR-build binning parameters
#define BSHIFT 10
#define BUCKN (1 << BSHIFT)                 // 1024 nodes per bucket
#define NBUCK 98                            // buckets of 1024 nodes
#define EPB 3840                            // edges per bin block
#define NBIN ((N_EDGES + EPB - 1) / EPB)    // 417
#define CAP 24576                           // LDS staging capacity

// MFMA layer tile
#define LBM 128                             // rows per block (4 waves x 32)

typedef __attribute__((ext_vector_type(8))) short bf16x8;
typedef __attribute__((ext_vector_type(4))) float f32x4;

__device__ __forceinline__ float bf2f(unsigned short u) {
    return __uint_as_float(((unsigned int)u) << 16);
}
__device__ __forceinline__ unsigned short f2bf(float f) {
    unsigned int u = __float_as_uint(f);
    u += 0x7FFFu + ((u >> 16) & 1u);        // round-to-nearest-even
    return (unsigned short)(u >> 16);
}
// A-panel LDS addressing: row-major [128][256] ushorts, 16B slots XOR-swizzled
// by row (c16 ^= row&7) so 16-row frag reads spread across all 32 banks (G4).
__device__ __forceinline__ int at_off(int row, int c16) {
    return row * 256 + ((c16 ^ (row & 7)) << 3);   // in ushorts
}

// ---------------- bucket histogram ----------------
__global__ __launch_bounds__(256) void hist_bucket(const int* __restrict__ dst,
                                                   int* __restrict__ histg) {
    __shared__ int h[NBUCK];
    int t = threadIdx.x;
    if (t < NBUCK) h[t] = 0;
    __syncthreads();
    int base = blockIdx.x * EPB;
    #pragma unroll
    for (int i = 0; i < EPB / 256; ++i) {
        int e = base + i * 256 + t;
        if (e < N_EDGES) atomicAdd(&h[dst[e] >> BSHIFT], 1);
    }
    __syncthreads();
    if (t < NBUCK && h[t]) atomicAdd(&histg[t], h[t]);
}

// ---------------- bucket base scan ----------------
__global__ __launch_bounds__(128) void scan_bucket(const int* __restrict__ histg,
                                                   int* __restrict__ bbase,
                                                   int* __restrict__ bcur) {
    __shared__ int sb[128];
    int t = threadIdx.x;
    int v = (t < NBUCK) ? histg[t] : 0;
    sb[t] = v;
    __syncthreads();
    for (int off = 1; off < 128; off <<= 1) {
        int x = sb[t];
        if (t >= off) x += sb[t - off];
        __syncthreads();
        sb[t] = x;
        __syncthreads();
    }
    if (t < NBUCK) { bbase[t] = sb[t] - v; bcur[t] = sb[t] - v; }
    if (t == NBUCK - 1) bbase[NBUCK] = sb[t];
}

// ---------------- bin pass (locality-creating LDS counting sort) ----------------
__global__ __launch_bounds__(256) void bin_pass(const int* __restrict__ src,
                                                const int* __restrict__ dst,
                                                int* __restrict__ bcur,
                                                uint2* __restrict__ stash) {
    __shared__ int srcL[EPB];
    __shared__ int dstL[EPB];
    __shared__ int hist[NBUCK], lex[NBUCK], lcur[NBUCK], gbase[NBUCK];
    __shared__ int sb[128];
    int t = threadIdx.x;
    if (t < NBUCK) hist[t] = 0;
    __syncthreads();
    int base = blockIdx.x * EPB;
    #pragma unroll
    for (int i = 0; i < EPB / 256; ++i) {
        int e = base + i * 256 + t;
        if (e < N_EDGES) atomicAdd(&hist[dst[e] >> BSHIFT], 1);
    }
    __syncthreads();
    {
        int v = (t < NBUCK) ? hist[t] : 0;
        if (t < 128) sb[t] = v;
        __syncthreads();
        for (int off = 1; off < 128; off <<= 1) {
            int x = 0;
            if (t < 128) { x = sb[t]; if (t >= off) x += sb[t - off]; }
            __syncthreads();
            if (t < 128) sb[t] = x;
            __syncthreads();
        }
        if (t < NBUCK) {
            int ex = sb[t] - hist[t];
            lex[t] = ex; lcur[t] = ex;
            gbase[t] = atomicAdd(&bcur[t], hist[t]);
        }
    }
    __syncthreads();
    #pragma unroll
    for (int i = 0; i < EPB / 256; ++i) {
        int e = base + i * 256 + t;
        if (e < N_EDGES) {
            int d = dst[e];
            int p = atomicAdd(&lcur[d >> BSHIFT], 1);
            dstL[p] = d; srcL[p] = src[e];
        }
    }
    __syncthreads();
    int n_e = min(EPB, N_EDGES - base);
    #pragma unroll
    for (int i = 0; i < EPB / 256; ++i) {
        int idx = i * 256 + t;
        if (idx < n_e) {
            int lo = 0, hi = NBUCK - 1;
            while (lo < hi) { int mid = (lo + hi + 1) >> 1; if (lex[mid] <= idx) lo = mid; else hi = mid - 1; }
            int g = gbase[lo] + (idx - lex[lo]);
            stash[g] = make_uint2((unsigned)dstL[idx], (unsigned)srcL[idx]);
        }
    }
}

// ---------------- fused CSR finalize: one block per bucket, all-LDS ----------------
__global__ __launch_bounds__(256) void csr_bucket(const uint2* __restrict__ stash,
                                                  const int* __restrict__ bbase,
                                                  int* __restrict__ offsets,
                                                  int* __restrict__ ends,
                                                  int* __restrict__ csr) {
    __shared__ int cnt[BUCKN];
    __shared__ int ex[BUCKN];
    __shared__ int sb[256];
    __shared__ int srcL[CAP];
    int k = blockIdx.x;
    int t = threadIdx.x;
    int beg = bbase[k], end = bbase[k + 1];
    int ne = end - beg;
    #pragma unroll
    for (int i = 0; i < BUCKN / 256; ++i) cnt[i * 256 + t] = 0;
    __syncthreads();
    for (int i = beg + t; i < end; i += 256)
        atomicAdd(&cnt[stash[i].x & (BUCKN - 1)], 1);
    __syncthreads();
    int c0 = cnt[t * 4], c1 = cnt[t * 4 + 1], c2 = cnt[t * 4 + 2], c3 = cnt[t * 4 + 3];
    int gs = c0 + c1 + c2 + c3;
    sb[t] = gs;
    __syncthreads();
    for (int off = 1; off < 256; off <<= 1) {
        int x = sb[t];
        if (t >= off) x += sb[t - off];
        __syncthreads();
        sb[t] = x;
        __syncthreads();
    }
    int gbase_ = sb[t] - gs;
    ex[t * 4]     = gbase_;
    ex[t * 4 + 1] = gbase_ + c0;
    ex[t * 4 + 2] = gbase_ + c0 + c1;
    ex[t * 4 + 3] = gbase_ + c0 + c1 + c2;
    __syncthreads();
    #pragma unroll
    for (int i = 0; i < BUCKN / 256; ++i) cnt[i * 256 + t] = ex[i * 256 + t];
    __syncthreads();
    for (int i = beg + t; i < end; i += 256) {
        uint2 p = stash[i];
        int pos = atomicAdd(&cnt[p.x & (BUCKN - 1)], 1);
        if (pos < CAP) srcL[pos] = (int)p.y;
        else csr[beg + pos] = (int)p.y;
    }
    __syncthreads();
    int lim = min(ne, CAP);
    for (int i = t; i < lim; i += 256) csr[beg + i] = srcL[i];
    int nb = k << BSHIFT;
    #pragma unroll
    for (int i = 0; i < BUCKN / 256; ++i) {
        int idx = i * 256 + t;
        int node = nb + idx;
        if (node < N_NODES) {
            offsets[node] = beg + ex[idx];
            ends[node] = beg + cnt[idx];
        }
    }
}

// ---------------- weight prep: Wt[n][k] = bf16 of [W_l; W_r][k][n] ----------------
__global__ __launch_bounds__(256) void prep_w(const float* __restrict__ Wl,
                                              const float* __restrict__ Wr,
                                              unsigned short* __restrict__ Wt) {
    int idx = blockIdx.x * 256 + threadIdx.x;
    if (idx < HIDDEN * 2 * HIDDEN) {
        int n = idx >> 8, k = idx & 255;
        float v = (k < HIDDEN) ? Wl[k * HIDDEN + n] : Wr[(k - HIDDEN) * HIDDEN + n];
        Wt[n * 256 + k] = f2bf(v);
    }
}

// ---------------- input projection -> bf16 h ----------------
__global__ __launch_bounds__(256) void proj_kernel(const float* __restrict__ x,
                                                   const float* __restrict__ W,
                                                   const float* __restrict__ b,
                                                   unsigned short* __restrict__ hb) {
    __shared__ float ws[N_FEAT][HIDDEN];
    __shared__ float bs[HIDDEN];
    __shared__ float xs[64][N_FEAT];
    int t = threadIdx.x;
    #pragma unroll
    for (int i = 0; i < 4; ++i)
        ((float4*)&ws[0][0])[t + i * 256] = ((const float4*)W)[t + i * 256];
    if (t < 32) ((float4*)bs)[t] = ((const float4*)b)[t];
    int base = blockIdx.x * 64;
    #pragma unroll
    for (int i = 0; i < 2; ++i) {
        int f4 = t + i * 256;
        int node = base + (f4 >> 3);
        float4 v = make_float4(0.f, 0.f, 0.f, 0.f);
        if (node < N_NODES) v = ((const float4*)x)[(size_t)node * 8 + (f4 & 7)];
        ((float4*)&xs[0][0])[f4] = v;
    }
    __syncthreads();
    int c0 = (t & 31) * 4;
    int nslot = t >> 5;
    for (int it = 0; it < 8; ++it) {
        int nl = nslot + it * 8;
        int node = base + nl;
        float acc0 = bs[c0], acc1 = bs[c0 + 1], acc2 = bs[c0 + 2], acc3 = bs[c0 + 3];
        #pragma unroll
        for (int k = 0; k < N_FEAT; ++k) {
            float a = xs[nl][k];
            float4 w = *(const float4*)&ws[k][c0];
            acc0 += a * w.x; acc1 += a * w.y; acc2 += a * w.z; acc3 += a * w.w;
        }
        if (node < N_NODES) {
            ushort4 o;
            o.x = f2bf(acc0); o.y = f2bf(acc1); o.z = f2bf(acc2); o.w = f2bf(acc3);
            *(ushort4*)&hb[(size_t)node * HIDDEN + c0] = o;
        }
    }
}

// ---------------- gather (bf16, 16 lanes/node x 16B): agg_b[n] = mean of hb[src] ----------------
__global__ __launch_bounds__(256) void gather_kernel(const unsigned short* __restrict__ hb,
                                                     const int* __restrict__ csr,
                                                     const int* __restrict__ offsets,
                                                     const int* __restrict__ ends,
                                                     unsigned short* __restrict__ aggb) {
    int node = (int)(((size_t)blockIdx.x * blockDim.x + threadIdx.x) >> 4);
    int lane = threadIdx.x & 15;
    if (node >= N_NODES) return;
    int st = offsets[node];
    int en = ends[node];
    int dn = en - st;
    float a0[8] = {}, a1[8] = {}, a2[8] = {}, a3[8] = {};
    const size_t loff = (size_t)lane * 8;
    int i = st;
    for (; i + 4 <= en; i += 4) {
        int s0 = csr[i], s1 = csr[i + 1], s2 = csr[i + 2], s3 = csr[i + 3];
        uint4 v0 = *(const uint4*)(hb + (size_t)s0 * HIDDEN + loff);
        uint4 v1 = *(const uint4*)(hb + (size_t)s1 * HIDDEN + loff);
        uint4 v2 = *(const uint4*)(hb + (size_t)s2 * HIDDEN + loff);
        uint4 v3 = *(const uint4*)(hb + (size_t)s3 * HIDDEN + loff);
        const unsigned int* u0 = &v0.x;
        const unsigned int* u1 = &v1.x;
        const unsigned int* u2 = &v2.x;
        const unsigned int* u3 = &v3.x;
        #pragma unroll
        for (int j = 0; j < 4; ++j) {
            a0[2*j]   += bf2f((unsigned short)(u0[j] & 0xFFFFu));
            a0[2*j+1] += bf2f((unsigned short)(u0[j] >> 16));
            a1[2*j]   += bf2f((unsigned short)(u1[j] & 0xFFFFu));
            a1[2*j+1] += bf2f((unsigned short)(u1[j] >> 16));
            a2[2*j]   += bf2f((unsigned short)(u2[j] & 0xFFFFu));
            a2[2*j+1] += bf2f((unsigned short)(u2[j] >> 16));
            a3[2*j]   += bf2f((unsigned short)(u3[j] & 0xFFFFu));
            a3[2*j+1] += bf2f((unsigned short)(u3[j] >> 16));
        }
    }
    for (; i < en; ++i) {
        int s0 = csr[i];
        uint4 v0 = *(const uint4*)(hb + (size_t)s0 * HIDDEN + loff);
        const unsigned int* u0 = &v0.x;
        #pragma unroll
        for (int j = 0; j < 4; ++j) {
            a0[2*j]   += bf2f((unsigned short)(u0[j] & 0xFFFFu));
            a0[2*j+1] += bf2f((unsigned short)(u0[j] >> 16));
        }
    }
    float inv = 1.0f / fmaxf((float)dn, 1.0f);
    uint4 r;
    unsigned int* ru = &r.x;
    #pragma unroll
    for (int j = 0; j < 4; ++j) {
        unsigned short lo = f2bf(((a0[2*j]   + a1[2*j])   + (a2[2*j]   + a3[2*j]))   * inv);
        unsigned short hi = f2bf(((a0[2*j+1] + a1[2*j+1]) + (a2[2*j+1] + a3[2*j+1])) * inv);
        ru[j] = (unsigned int)lo | ((unsigned int)hi << 16);
    }
    *(uint4*)(aggb + (size_t)node * HIDDEN + loff) = r;
}

// ---------------- MFMA layer v2: full K=256 panel in LDS, ONE barrier ----------------
// v1 had 16 syncthreads/block with 16 MFMAs between each -> latency-bound
// (MfmaUtil 2.8%, VALUBusy 14.6%, Occ 17.5%). v2 stages [aggb|hb] rows (512B
// x 128 = 64KB, XOR-swizzled 16B slots) once, then runs 128 MFMAs/wave
// barrier-free with B streamed from L2-resident Wt.
__global__ __launch_bounds__(256) void layer_mfma(const unsigned short* __restrict__ aggb,
                                                  const unsigned short* __restrict__ Wt,
                                                  const float* __restrict__ b_l,
                                                  const float* __restrict__ gamma_,
                                                  const float* __restrict__ beta_,
                                                  unsigned short* __restrict__ hb) {
    __shared__ unsigned short At[LBM * 256];   // 64KB
    int t = threadIdx.x;
    int row0 = blockIdx.x * LBM;
    int w = t >> 6;
    int l = t & 63;
    int c = l & 15;
    int g = l >> 4;
    // stage full A-panel: 128 rows x 32 x 16B chunks (c16<16 from aggb, else hb)
    #pragma unroll
    for (int i = 0; i < 16; ++i) {
        int ch = i * 256 + t;
        int row = ch >> 5, c16 = ch & 31;
        int node = row0 + row;
        uint4 v = make_uint4(0u, 0u, 0u, 0u);
        if (node < N_NODES) {
            const unsigned short* srcp = (c16 < 16)
                ? (aggb + (size_t)node * HIDDEN + c16 * 8)
                : (hb   + (size_t)node * HIDDEN + (c16 - 16) * 8);
            v = *(const uint4*)srcp;
        }
        *(uint4*)&At[at_off(row, c16)] = v;
    }
    __syncthreads();   // the only barrier
    f32x4 acc[2][8];
    #pragma unroll
    for (int fr = 0; fr < 2; ++fr)
        #pragma unroll
        for (int nf = 0; nf < 8; ++nf)
            acc[fr][nf] = (f32x4){0.f, 0.f, 0.f, 0.f};
    int r0 = w * 32 + c;
    #pragma unroll
    for (int kt = 0; kt < 8; ++kt) {
        bf16x8 a0 = *(const bf16x8*)&At[at_off(r0,      kt * 4 + g)];
        bf16x8 a1 = *(const bf16x8*)&At[at_off(r0 + 16, kt * 4 + g)];
        #pragma unroll
        for (int nf = 0; nf < 8; ++nf) {
            bf16x8 b = *(const bf16x8*)(Wt + (size_t)(nf * 16 + c) * 256 + kt * 32 + g * 8);
            acc[0][nf] = __builtin_amdgcn_mfma_f32_16x16x32_bf16(a0, b, acc[0][nf], 0, 0, 0);
            acc[1][nf] = __builtin_amdgcn_mfma_f32_16x16x32_bf16(a1, b, acc[1][nf], 0, 0, 0);
        }
    }
    // epilogue: +b_l, ELU, LayerNorm (rows live across the 16 lanes sharing g)
    float bl[8], ga[8], be[8];
    #pragma unroll
    for (int nf = 0; nf < 8; ++nf) {
        int col = nf * 16 + c;
        bl[nf] = b_l[col]; ga[nf] = gamma_[col]; be[nf] = beta_[col];
    }
    const float inv128 = 1.0f / 128.0f;
    #pragma unroll
    for (int fr = 0; fr < 2; ++fr) {
        #pragma unroll
        for (int r = 0; r < 4; ++r) {
            int node = row0 + w * 32 + fr * 16 + g * 4 + r;
            float v[8];
            float s = 0.f, sq = 0.f;
            #pragma unroll
            for (int nf = 0; nf < 8; ++nf) {
                float xv = acc[fr][nf][r] + bl[nf];
                xv = (xv > 0.f) ? xv : expm1f(xv);
                v[nf] = xv; s += xv; sq += xv * xv;
            }
            #pragma unroll
            for (int m = 8; m >= 1; m >>= 1) {
                s += __shfl_xor(s, m, 64);
                sq += __shfl_xor(sq, m, 64);
            }
            float mu = s * inv128;
            float var = sq * inv128 - mu * mu;
            float rstd = rsqrtf(var + LN_EPS);
            if (node < N_NODES) {
                #pragma unroll
                for (int nf = 0; nf < 8; ++nf)
                    hb[(size_t)node * HIDDEN + nf * 16 + c] =
                        f2bf((v[nf] - mu) * rstd * ga[nf] + be[nf]);
            }
        }
    }
}

// ---------------- fused pool + heads (bf16 h) ----------------
__global__ __launch_bounds__(256) void pool_head_kernel(const unsigned short* __restrict__ hb,
                                                        const int* __restrict__ batch,
                                                        const float* __restrict__ W_mem,
                                                        const float* __restrict__ b_mem,
                                                        const float* __restrict__ W_time,
                                                        const float* __restrict__ b_time,
                                                        float* __restrict__ out) {
    __shared__ float red[8][HIDDEN];
    int g = blockIdx.x;
    int t = threadIdx.x;
    int lane = t & 31;
    int grp = t >> 5;
    int lo = 0, hi = N_NODES;
    while (lo < hi) { int mid = (lo + hi) >> 1; if (batch[mid] < g) lo = mid + 1; else hi = mid; }
    int start = lo;
    hi = N_NODES;
    while (lo < hi) { int mid = (lo + hi) >> 1; if (batch[mid] < g + 1) lo = mid + 1; else hi = mid; }
    int end = lo;
    float a0 = 0.f, a1 = 0.f, a2 = 0.f, a3 = 0.f;
    for (int n = start + grp; n < end; n += 8) {
        ushort4 v = *(const ushort4*)(hb + (size_t)n * HIDDEN + lane * 4);
        a0 += bf2f(v.x); a1 += bf2f(v.y); a2 += bf2f(v.z); a3 += bf2f(v.w);
    }
    red[grp][lane * 4 + 0] = a0; red[grp][lane * 4 + 1] = a1;
    red[grp][lane * 4 + 2] = a2; red[grp][lane * 4 + 3] = a3;
    __syncthreads();
    if (t < HIDDEN) {
        float s = 0.f;
        #pragma unroll
        for (int i = 0; i < 8; ++i) s += red[i][t];
        float ic = 1.0f / fmaxf((float)(end - start), 1.0f);
        red[0][t] = s * ic;
    }
    __syncthreads();
    if (t < 64) {
        float p0 = red[0][t], p1 = red[0][t + 64];
        float dm = p0 * W_mem[t] + p1 * W_mem[t + 64];
        float dtv = p0 * W_time[t] + p1 * W_time[t + 64];
        #pragma unroll
        for (int m = 32; m >= 1; m >>= 1) {
            dm += __shfl_xor(dm, m, 64);
            dtv += __shfl_xor(dtv, m, 64);
        }
        if (t == 0) {
            out[g] = dm + b_mem[0];
            out[N_GRAPHS + g] = dtv + b_time[0];
        }
    }
}

extern "C" void kernel_launch(void* const* d_in, const int* in_sizes, int n_in,
                              void* d_out, int out_size, void* d_ws, size_t ws_size,
                              hipStream_t stream) {
    const float* x      = (const float*)d_in[0];
    const int*   edge   = (const int*)d_in[1];
    const int*   batch  = (const int*)d_in[2];
    const float* W_op   = (const float*)d_in[3];
    const float* b_op   = (const float*)d_in[4];
    const float* W_l    = (const float*)d_in[5];
    const float* b_l    = (const float*)d_in[6];
    const float* W_r    = (const float*)d_in[7];
    const float* gamma_ = (const float*)d_in[8];
    const float* beta_  = (const float*)d_in[9];
    const float* W_mem  = (const float*)d_in[10];
    const float* b_mem  = (const float*)d_in[11];
    const float* W_time = (const float*)d_in[12];
    const float* b_time = (const float*)d_in[13];
    const int* src = edge;
    const int* dst = edge + N_EDGES;

    char* ws = (char*)d_ws;
    const size_t hb_bytes = (size_t)N_NODES * HIDDEN * sizeof(unsigned short);  // 25.6MB
    unsigned short* hb    = (unsigned short*)ws;
    unsigned short* aggb  = (unsigned short*)(ws + hb_bytes);
    char*  p       = ws + 2 * hb_bytes;
    unsigned short* Wt = (unsigned short*)p;  p += (size_t)HIDDEN * 2 * HIDDEN * 2;  // 64KB
    int*   offsets = (int*)p;                 p += (size_t)N_NODES * 4;
    int*   ends    = (int*)p;                 p += (size_t)N_NODES * 4;
    int*   csr     = (int*)p;                 p += (size_t)N_EDGES * 4;
    int*   histg   = (int*)p;                 p += 512;
    int*   bbase   = (int*)p;                 p += 512;
    int*   bcur    = (int*)p;                 p += 512;
    // stash (12.8MB) aliases aggb (25.6MB): aggb is dead until first gather,
    // which runs only after csr_bucket has consumed the stash.
    uint2* stash   = (uint2*)aggb;

    hipMemsetAsync(histg, 0, NBUCK * sizeof(int), stream);

    // binned CSR build: hist -> bases -> LDS-sort to stash -> all-LDS finalize
    hist_bucket<<<NBIN, 256, 0, stream>>>(dst, histg);
    scan_bucket<<<1, 128, 0, stream>>>(histg, bbase, bcur);
    bin_pass<<<NBIN, 256, 0, stream>>>(src, dst, bcur, stash);
    csr_bucket<<<NBUCK, 256, 0, stream>>>(stash, bbase, offsets, ends, csr);

    // weights -> bf16 transposed; input projection -> bf16 h
    prep_w<<<128, 256, 0, stream>>>(W_l, W_r, Wt);
    proj_kernel<<<(N_NODES + 63) / 64, 256, 0, stream>>>(x, W_op, b_op, hb);

    // layers
    for (int layer = 0; layer < 2; ++layer) {
        gather_kernel<<<(int)(((size_t)N_NODES * 16 + 255) / 256), 256, 0, stream>>>(
            hb, csr, offsets, ends, aggb);
        layer_mfma<<<(N_NODES + LBM - 1) / LBM, 256, 0, stream>>>(
            aggb, Wt, b_l, gamma_, beta_, hb);
    }

    // fused pooling + heads
    pool_head_kernel<<<N_GRAPHS, 256, 0, stream>>>(hb, batch, W_mem, b_mem, W_time, b_time, (float*)d_out);
}